// Round 1
// baseline (214.555 us; speedup 1.0000x reference)
//
#include <hip/hip_runtime.h>
#include <stdint.h>
#include <math.h>

#define C_DIM 128
#define N_TOK 4096
#define NB 4
#define LOG2E 1.4426950408889634f

typedef __attribute__((ext_vector_type(8))) short bf16x8;
typedef __attribute__((ext_vector_type(4))) float f32x4;

__device__ __forceinline__ unsigned short f2bf(float f) {
  unsigned u = __builtin_bit_cast(unsigned, f);
  unsigned r = (u + 0x7FFFu + ((u >> 16) & 1u)) >> 16;
  return (unsigned short)r;
}
__device__ __forceinline__ float bf2f(unsigned short h) {
  return __builtin_bit_cast(float, ((unsigned)h) << 16);
}
__device__ __forceinline__ void gload_lds16(const void* g, void* l) {
  __builtin_amdgcn_global_load_lds((const __attribute__((address_space(1))) void*)g,
                                   (__attribute__((address_space(3))) void*)l,
                                   16, 0, 0);
}

// ---------------- Stage 1: conv1x1(c->2c)+BN, emit q [b][n][c] bf16, vT [b][c][n] bf16 ----------------
// GEMM: t[o][n] = sum_c W[o][c] * x[b][c][n], 3-term bf16 split for ~fp32 precision.
__global__ __launch_bounds__(256) void proj_in_kernel(
    const float* __restrict__ x, const float* __restrict__ w_inp,
    const float* __restrict__ b_inp, const float* __restrict__ gamma,
    const float* __restrict__ beta, const float* __restrict__ mean,
    const float* __restrict__ var,
    unsigned short* __restrict__ q, unsigned short* __restrict__ vT) {
  __shared__ char smem[35840];
  unsigned short* xh = (unsigned short*)smem;            // [64][136] bf16 hi
  unsigned short* xl = (unsigned short*)(smem + 17408);  // [64][136] bf16 lo

  const int tid = threadIdx.x;
  const int b = blockIdx.x >> 6;
  const int n0 = (blockIdx.x & 63) << 6;
  const int lane = tid & 63;
  const int wave = tid >> 6;
  const int l15 = lane & 15, lg = lane >> 4;

  // stage x tile [128 c][64 n] -> LDS transposed [n][c] as hi/lo bf16
  {
    const int c = tid >> 1;
    const int j0 = (tid & 1) * 32;
    const float* src = x + ((size_t)b * C_DIM + c) * N_TOK + n0 + j0;
#pragma unroll
    for (int j = 0; j < 32; j += 4) {
      float4 v4 = *(const float4*)(src + j);
#pragma unroll
      for (int e = 0; e < 4; e++) {
        float f = (&v4.x)[e];
        unsigned short hi = f2bf(f);
        unsigned short lo = f2bf(f - bf2f(hi));
        int n = j0 + j + e;
        xh[n * 136 + c] = hi;
        xl[n * 136 + c] = lo;
      }
    }
  }
  __syncthreads();

  f32x4 acc[4][4];
#pragma unroll
  for (int i = 0; i < 4; i++)
#pragma unroll
    for (int j = 0; j < 4; j++) acc[i][j] = {0.f, 0.f, 0.f, 0.f};

#pragma unroll
  for (int ks = 0; ks < 4; ks++) {
    bf16x8 ah[4], al[4];
#pragma unroll
    for (int ot = 0; ot < 4; ot++) {
      const int o = wave * 64 + ot * 16 + l15;
      const float* wp = w_inp + o * C_DIM + ks * 32 + lg * 8;
      float4 w0 = *(const float4*)wp;
      float4 w1 = *(const float4*)(wp + 4);
#pragma unroll
      for (int e = 0; e < 8; e++) {
        float f = (e < 4) ? (&w0.x)[e] : (&w1.x)[e - 4];
        unsigned short hi = f2bf(f);
        ah[ot][e] = (short)hi;
        al[ot][e] = (short)f2bf(f - bf2f(hi));
      }
    }
#pragma unroll
    for (int nt = 0; nt < 4; nt++) {
      const int off = (nt * 16 + l15) * 136 + ks * 32 + lg * 8;
      bf16x8 bh = *(const bf16x8*)(xh + off);
      bf16x8 bl = *(const bf16x8*)(xl + off);
#pragma unroll
      for (int ot = 0; ot < 4; ot++) {
        acc[ot][nt] = __builtin_amdgcn_mfma_f32_16x16x32_bf16(ah[ot], bh, acc[ot][nt], 0, 0, 0);
        acc[ot][nt] = __builtin_amdgcn_mfma_f32_16x16x32_bf16(ah[ot], bl, acc[ot][nt], 0, 0, 0);
        acc[ot][nt] = __builtin_amdgcn_mfma_f32_16x16x32_bf16(al[ot], bh, acc[ot][nt], 0, 0, 0);
      }
    }
  }
  __syncthreads();  // reuse smem

  unsigned short* qT = (unsigned short*)smem;             // [64][136]
  unsigned short* vTl = (unsigned short*)(smem + 17408);  // [128][72]

#pragma unroll
  for (int ot = 0; ot < 4; ot++) {
#pragma unroll
    for (int r = 0; r < 4; r++) {
      const int o = wave * 64 + ot * 16 + lg * 4 + r;
      float A = gamma[o] * rsqrtf(var[o] + 1e-5f);
      float Bo = beta[o] + (b_inp[o] - mean[o]) * A;
#pragma unroll
      for (int nt = 0; nt < 4; nt++) {
        float val = acc[ot][nt][r] * A + Bo;
        unsigned short hv = f2bf(val);
        int n = nt * 16 + l15;
        if (wave < 2) {
          qT[n * 136 + o] = hv;
        } else {
          vTl[(o - 128) * 72 + n] = hv;
        }
      }
    }
  }
  __syncthreads();
  // write q rows [n0+j][0..128)
  {
    int j = tid >> 2, c0 = (tid & 3) * 32;
    unsigned short* dst = q + ((size_t)b * N_TOK + n0 + j) * C_DIM + c0;
    const unsigned short* s = qT + j * 136 + c0;
#pragma unroll
    for (int i = 0; i < 32; i += 8) *(bf16x8*)(dst + i) = *(const bf16x8*)(s + i);
  }
  // write vT rows [c][n0+h..]
  {
    int c = tid >> 1, h = (tid & 1) * 32;
    unsigned short* dst = vT + ((size_t)b * C_DIM + c) * N_TOK + n0 + h;
    const unsigned short* s = vTl + c * 72 + h;
#pragma unroll
    for (int i = 0; i < 32; i += 8) *(bf16x8*)(dst + i) = *(const bf16x8*)(s + i);
  }
}

// ---------------- Stage 2: attention + fused project_out ----------------
// block = 4 waves, 64 q-rows (16/wave). Sweep1: online max/sum. Sweep2: recompute S,
// write atn fp32, PV accumulate, then fused y*w_out+b_out -> yout [b][c][n].
__global__ __launch_bounds__(256) void attn_kernel(
    const unsigned short* __restrict__ q, const unsigned short* __restrict__ vT,
    const float* __restrict__ w_out, const float* __restrict__ b_out,
    float* __restrict__ yout, float* __restrict__ atn) {
  __shared__ char smem[74752];
  // [0,16K) kbuf0, [16K,32K) kbuf1, [32K,48K) vbuf0, [48K,64K) vbuf1, [64K+) per-wave p [16][72] bf16

  const int tid = threadIdx.x;
  const int lane = tid & 63;
  const int wave = tid >> 6;
  const int l15 = lane & 15, lg = lane >> 4, l7 = lane & 7;
  const int b = blockIdx.x >> 6;
  const int q0 = (blockIdx.x & 63) << 6;
  const int row0 = q0 + wave * 16;

  const unsigned short* qb = q + (size_t)b * N_TOK * C_DIM;
  const unsigned short* vb = vT + (size_t)b * C_DIM * N_TOK;

  // Q A-frags (rows row0+l15, k = ks*32 + lg*8 + e)
  bf16x8 qf[4];
#pragma unroll
  for (int ks = 0; ks < 4; ks++)
    qf[ks] = *(const bf16x8*)(qb + (size_t)(row0 + l15) * C_DIM + ks * 32 + lg * 8);

  int koff[4];  // swizzled within-row byte offset: (ks*64 + lg*16) ^ (l7*16)
#pragma unroll
  for (int ks = 0; ks < 4; ks++) koff[ks] = (ks * 64 + lg * 16) ^ (l7 * 16);
  const int krow = l15 * 256;  // K row byte base within nt-group
  const int vrow = l15 * 128;  // V row byte base within ct-group

  auto stageK = [&](int kt, int buf) {
    char* base = smem + buf * 16384;
#pragma unroll
    for (int i = 0; i < 4; i++) {
      int lin = i * 256 + tid;
      int key = lin >> 4;
      int c = ((lin & 15) * 8) ^ ((key & 7) * 8);  // inverse swizzle on source
      gload_lds16(qb + (size_t)(kt * 64 + key) * C_DIM + c, base + lin * 16);
    }
  };
  auto stageV = [&](int kt, int buf) {
    char* base = smem + 32768 + buf * 16384;
#pragma unroll
    for (int i = 0; i < 4; i++) {
      int lin = i * 256 + tid;
      int c = lin >> 3;
      int key = ((lin & 7) * 8) ^ ((c & 7) * 8);
      gload_lds16(vb + (size_t)c * N_TOK + kt * 64 + key, base + lin * 16);
    }
  };

  const float scale = 0.08838834764831845f;  // 1/sqrt(128)
  float m[4], l[4];
#pragma unroll
  for (int r = 0; r < 4; r++) { m[r] = -1e30f; l[r] = 0.f; }

  // ---- Sweep 1: row max + sum ----
  stageK(0, 0);
  __syncthreads();
  for (int kt = 0; kt < 64; kt++) {
    if (kt + 1 < 64) stageK(kt + 1, (kt + 1) & 1);
    const char* kb = smem + (kt & 1) * 16384;
    float s_all[4][4];
#pragma unroll
    for (int nt = 0; nt < 4; nt++) {
      f32x4 acc = {0.f, 0.f, 0.f, 0.f};
#pragma unroll
      for (int ks = 0; ks < 4; ks++) {
        bf16x8 bk = *(const bf16x8*)(kb + nt * 4096 + krow + koff[ks]);
        acc = __builtin_amdgcn_mfma_f32_16x16x32_bf16(qf[ks], bk, acc, 0, 0, 0);
      }
#pragma unroll
      for (int r = 0; r < 4; r++) s_all[nt][r] = acc[r] * scale;
    }
#pragma unroll
    for (int r = 0; r < 4; r++) {
      float mx = fmaxf(fmaxf(s_all[0][r], s_all[1][r]), fmaxf(s_all[2][r], s_all[3][r]));
      mx = fmaxf(mx, __shfl_xor(mx, 1));
      mx = fmaxf(mx, __shfl_xor(mx, 2));
      mx = fmaxf(mx, __shfl_xor(mx, 4));
      mx = fmaxf(mx, __shfl_xor(mx, 8));
      float mn = fmaxf(m[r], mx);
      float sum = 0.f;
#pragma unroll
      for (int nt = 0; nt < 4; nt++) sum += exp2f((s_all[nt][r] - mn) * LOG2E);
      sum += __shfl_xor(sum, 1);
      sum += __shfl_xor(sum, 2);
      sum += __shfl_xor(sum, 4);
      sum += __shfl_xor(sum, 8);
      l[r] = l[r] * exp2f((m[r] - mn) * LOG2E) + sum;
      m[r] = mn;
    }
    __syncthreads();
  }

  float invl[4];
#pragma unroll
  for (int r = 0; r < 4; r++) invl[r] = 1.0f / l[r];

  // ---- Sweep 2: recompute S, write atn, PV ----
  f32x4 yacc[8];
#pragma unroll
  for (int ct = 0; ct < 8; ct++) yacc[ct] = {0.f, 0.f, 0.f, 0.f};

  stageK(0, 0);
  stageV(0, 0);
  __syncthreads();
  unsigned short* pb = (unsigned short*)(smem + 65536 + wave * 2304);
  float* atnb = atn + ((size_t)b * N_TOK + row0) * N_TOK;

  for (int kt = 0; kt < 64; kt++) {
    if (kt + 1 < 64) { stageK(kt + 1, (kt + 1) & 1); stageV(kt + 1, (kt + 1) & 1); }
    const char* kb = smem + (kt & 1) * 16384;
    const char* vbf = smem + 32768 + (kt & 1) * 16384;
#pragma unroll
    for (int nt = 0; nt < 4; nt++) {
      f32x4 acc = {0.f, 0.f, 0.f, 0.f};
#pragma unroll
      for (int ks = 0; ks < 4; ks++) {
        bf16x8 bk = *(const bf16x8*)(kb + nt * 4096 + krow + koff[ks]);
        acc = __builtin_amdgcn_mfma_f32_16x16x32_bf16(qf[ks], bk, acc, 0, 0, 0);
      }
#pragma unroll
      for (int r = 0; r < 4; r++) {
        float p = exp2f((acc[r] * scale - m[r]) * LOG2E) * invl[r];
        atnb[(size_t)(lg * 4 + r) * N_TOK + kt * 64 + nt * 16 + l15] = p;
        pb[(lg * 4 + r) * 72 + nt * 16 + l15] = (unsigned short)f2bf(p);
      }
    }
    // PV: A = P [16 rows][64 keys] via per-wave LDS, B = V from swizzled vbuf
#pragma unroll
    for (int ks2 = 0; ks2 < 2; ks2++) {
      bf16x8 ap = *(const bf16x8*)(pb + l15 * 72 + ks2 * 32 + lg * 8);
#pragma unroll
      for (int ct = 0; ct < 8; ct++) {
        bf16x8 bv = *(const bf16x8*)(vbf + ct * 2048 + vrow + koff[ks2]);
        yacc[ct] = __builtin_amdgcn_mfma_f32_16x16x32_bf16(ap, bv, yacc[ct], 0, 0, 0);
      }
    }
    __syncthreads();
  }

  // ---- fused project_out: out[n][co] = sum_c y[n][c]*w_out[co][c] + b_out[co] ----
  __syncthreads();
  unsigned short* yl = (unsigned short*)(smem + wave * 16384);  // [16][136] bf16
  float* ol = (float*)(smem + wave * 16384 + 4608);             // [128][20] f32
#pragma unroll
  for (int ct = 0; ct < 8; ct++)
#pragma unroll
    for (int r = 0; r < 4; r++)
      yl[(lg * 4 + r) * 136 + ct * 16 + l15] = f2bf(yacc[ct][r]);

  bf16x8 af[4];
#pragma unroll
  for (int ks = 0; ks < 4; ks++)
    af[ks] = *(const bf16x8*)(yl + l15 * 136 + ks * 32 + lg * 8);

#pragma unroll
  for (int cot = 0; cot < 8; cot++) {
    f32x4 oacc = {0.f, 0.f, 0.f, 0.f};
#pragma unroll
    for (int ks = 0; ks < 4; ks++) {
      const float* wp = w_out + (cot * 16 + l15) * C_DIM + ks * 32 + lg * 8;
      float4 w0 = *(const float4*)wp;
      float4 w1 = *(const float4*)(wp + 4);
      bf16x8 bw;
#pragma unroll
      for (int e = 0; e < 8; e++) bw[e] = (short)f2bf((e < 4) ? (&w0.x)[e] : (&w1.x)[e - 4]);
      oacc = __builtin_amdgcn_mfma_f32_16x16x32_bf16(af[ks], bw, oacc, 0, 0, 0);
    }
    float bo = b_out[cot * 16 + l15];
#pragma unroll
    for (int r = 0; r < 4; r++) ol[(cot * 16 + l15) * 20 + lg * 4 + r] = oacc[r] + bo;
  }
  // coalesced write yout [b][co][row0..row0+16)
#pragma unroll
  for (int i = 0; i < 2; i++) {
    int co = i * 64 + lane;
    float* dst = yout + ((size_t)b * C_DIM + co) * N_TOK + row0;
    const float* s = ol + co * 20;
#pragma unroll
    for (int jj = 0; jj < 16; jj += 4) *(float4*)(dst + jj) = *(const float4*)(s + jj);
  }
}

extern "C" void kernel_launch(void* const* d_in, const int* in_sizes, int n_in,
                              void* d_out, int out_size, void* d_ws, size_t ws_size,
                              hipStream_t stream) {
  const float* x = (const float*)d_in[0];
  const float* w_inp = (const float*)d_in[1];
  const float* b_inp = (const float*)d_in[2];
  const float* gamma = (const float*)d_in[3];
  const float* beta = (const float*)d_in[4];
  const float* mean = (const float*)d_in[5];
  const float* var = (const float*)d_in[6];
  const float* w_out = (const float*)d_in[7];
  const float* b_out = (const float*)d_in[8];

  float* out = (float*)d_out;
  float* yout = out;                                   // [4][128][4096]
  float* atn = out + (size_t)NB * C_DIM * N_TOK;       // [4][4096][4096]

  unsigned short* q = (unsigned short*)d_ws;           // [4][4096][128] bf16
  unsigned short* vT = q + (size_t)NB * N_TOK * C_DIM; // [4][128][4096] bf16

  proj_in_kernel<<<256, 256, 0, stream>>>(x, w_inp, b_inp, gamma, beta, mean, var, q, vT);
  attn_kernel<<<256, 256, 0, stream>>>(q, vT, w_out, b_out, yout, atn);
}

// Round 2
// 212.790 us; speedup vs baseline: 1.0083x; 1.0083x over previous
//
#include <hip/hip_runtime.h>
#include <stdint.h>
#include <math.h>

#define C_DIM 128
#define N_TOK 4096
#define NB 4
#define LOG2E 1.4426950408889634f

typedef __attribute__((ext_vector_type(8))) short bf16x8;
typedef __attribute__((ext_vector_type(4))) float f32x4;

__device__ __forceinline__ unsigned short f2bf(float f) {
  unsigned u = __builtin_bit_cast(unsigned, f);
  unsigned r = (u + 0x7FFFu + ((u >> 16) & 1u)) >> 16;
  return (unsigned short)r;
}
__device__ __forceinline__ float bf2f(unsigned short h) {
  return __builtin_bit_cast(float, ((unsigned)h) << 16);
}
__device__ __forceinline__ void gload_lds16(const void* g, void* l) {
  __builtin_amdgcn_global_load_lds((const __attribute__((address_space(1))) void*)g,
                                   (__attribute__((address_space(3))) void*)l,
                                   16, 0, 0);
}

// ---------------- Stage 1: conv1x1(c->2c)+BN, emit q [b][n][c] bf16, vT [b][c][n] bf16 ----------------
__global__ __launch_bounds__(256) void proj_in_kernel(
    const float* __restrict__ x, const float* __restrict__ w_inp,
    const float* __restrict__ b_inp, const float* __restrict__ gamma,
    const float* __restrict__ beta, const float* __restrict__ mean,
    const float* __restrict__ var,
    unsigned short* __restrict__ q, unsigned short* __restrict__ vT) {
  __shared__ char smem[35840];
  unsigned short* xh = (unsigned short*)smem;            // [64][136] bf16 hi
  unsigned short* xl = (unsigned short*)(smem + 17408);  // [64][136] bf16 lo

  const int tid = threadIdx.x;
  const int b = blockIdx.x >> 6;
  const int n0 = (blockIdx.x & 63) << 6;
  const int lane = tid & 63;
  const int wave = tid >> 6;
  const int l15 = lane & 15, lg = lane >> 4;

  {
    const int c = tid >> 1;
    const int j0 = (tid & 1) * 32;
    const float* src = x + ((size_t)b * C_DIM + c) * N_TOK + n0 + j0;
#pragma unroll
    for (int j = 0; j < 32; j += 4) {
      float4 v4 = *(const float4*)(src + j);
#pragma unroll
      for (int e = 0; e < 4; e++) {
        float f = (&v4.x)[e];
        unsigned short hi = f2bf(f);
        unsigned short lo = f2bf(f - bf2f(hi));
        int n = j0 + j + e;
        xh[n * 136 + c] = hi;
        xl[n * 136 + c] = lo;
      }
    }
  }
  __syncthreads();

  f32x4 acc[4][4];
#pragma unroll
  for (int i = 0; i < 4; i++)
#pragma unroll
    for (int j = 0; j < 4; j++) acc[i][j] = {0.f, 0.f, 0.f, 0.f};

#pragma unroll
  for (int ks = 0; ks < 4; ks++) {
    bf16x8 ah[4], al[4];
#pragma unroll
    for (int ot = 0; ot < 4; ot++) {
      const int o = wave * 64 + ot * 16 + l15;
      const float* wp = w_inp + o * C_DIM + ks * 32 + lg * 8;
      float4 w0 = *(const float4*)wp;
      float4 w1 = *(const float4*)(wp + 4);
#pragma unroll
      for (int e = 0; e < 8; e++) {
        float f = (e < 4) ? (&w0.x)[e] : (&w1.x)[e - 4];
        unsigned short hi = f2bf(f);
        ah[ot][e] = (short)hi;
        al[ot][e] = (short)f2bf(f - bf2f(hi));
      }
    }
#pragma unroll
    for (int nt = 0; nt < 4; nt++) {
      const int off = (nt * 16 + l15) * 136 + ks * 32 + lg * 8;
      bf16x8 bh = *(const bf16x8*)(xh + off);
      bf16x8 bl = *(const bf16x8*)(xl + off);
#pragma unroll
      for (int ot = 0; ot < 4; ot++) {
        acc[ot][nt] = __builtin_amdgcn_mfma_f32_16x16x32_bf16(ah[ot], bh, acc[ot][nt], 0, 0, 0);
        acc[ot][nt] = __builtin_amdgcn_mfma_f32_16x16x32_bf16(ah[ot], bl, acc[ot][nt], 0, 0, 0);
        acc[ot][nt] = __builtin_amdgcn_mfma_f32_16x16x32_bf16(al[ot], bh, acc[ot][nt], 0, 0, 0);
      }
    }
  }
  __syncthreads();

  unsigned short* qT = (unsigned short*)smem;             // [64][136]
  unsigned short* vTl = (unsigned short*)(smem + 17408);  // [128][72]

#pragma unroll
  for (int ot = 0; ot < 4; ot++) {
#pragma unroll
    for (int r = 0; r < 4; r++) {
      const int o = wave * 64 + ot * 16 + lg * 4 + r;
      float A = gamma[o] * rsqrtf(var[o] + 1e-5f);
      float Bo = beta[o] + (b_inp[o] - mean[o]) * A;
#pragma unroll
      for (int nt = 0; nt < 4; nt++) {
        float val = acc[ot][nt][r] * A + Bo;
        unsigned short hv = f2bf(val);
        int n = nt * 16 + l15;
        if (wave < 2) {
          qT[n * 136 + o] = hv;
        } else {
          vTl[(o - 128) * 72 + n] = hv;
        }
      }
    }
  }
  __syncthreads();
  {
    int j = tid >> 2, c0 = (tid & 3) * 32;
    unsigned short* dst = q + ((size_t)b * N_TOK + n0 + j) * C_DIM + c0;
    const unsigned short* s = qT + j * 136 + c0;
#pragma unroll
    for (int i = 0; i < 32; i += 8) *(bf16x8*)(dst + i) = *(const bf16x8*)(s + i);
  }
  {
    int c = tid >> 1, h = (tid & 1) * 32;
    unsigned short* dst = vT + ((size_t)b * C_DIM + c) * N_TOK + n0 + h;
    const unsigned short* s = vTl + c * 72 + h;
#pragma unroll
    for (int i = 0; i < 32; i += 8) *(bf16x8*)(dst + i) = *(const bf16x8*)(s + i);
  }
}

// ---------------- Stage 2: attention + fused project_out ----------------
// Block: 32 q-rows, 4 waves = 2 rowgroups x 2 key-halves. Grid 512 -> 2 blocks/CU.
// Sweep1: partial (m,l) per key-half, merged via LDS. Sweep2: recompute S with final
// stats, write atn fp32, partial PV per key-half, merged via LDS, fused project_out.
__global__ __launch_bounds__(256) void attn_kernel(
    const unsigned short* __restrict__ q, const unsigned short* __restrict__ vT,
    const float* __restrict__ w_out, const float* __restrict__ b_out,
    float* __restrict__ yout, float* __restrict__ atn) {
  __shared__ char smem[71168];
  // [0,32K) kbuf dbuf, [32K,64K) vbuf dbuf, [64K..] per-wave p [16][40] bf16, stats

  const int tid = threadIdx.x;
  const int lane = tid & 63;
  const int wave = tid >> 6;
  const int rg = wave >> 1;   // row group 0/1
  const int kh = wave & 1;    // key half 0/1
  const int l15 = lane & 15, lg = lane >> 4, l7 = lane & 7;
  const int b = blockIdx.x >> 7;
  const int q0 = (blockIdx.x & 127) << 5;
  const int row0 = q0 + rg * 16;

  const unsigned short* qb = q + (size_t)b * N_TOK * C_DIM;
  const unsigned short* vb = vT + (size_t)b * C_DIM * N_TOK;

  // Q A-frags (rows row0+l15, k = ks*32 + lg*8 + e)
  bf16x8 qf[4];
#pragma unroll
  for (int ks = 0; ks < 4; ks++)
    qf[ks] = *(const bf16x8*)(qb + (size_t)(row0 + l15) * C_DIM + ks * 32 + lg * 8);

  int koff[4];  // swizzled within-row byte offset for K reads
#pragma unroll
  for (int ks = 0; ks < 4; ks++) koff[ks] = (ks * 64 + lg * 16) ^ (l7 * 16);
  const int koff2 = (kh * 64 + lg * 16) ^ (l7 * 16);  // V read, k-chunk = kh
  const int krow = l15 * 256;
  const int vrow = l15 * 128;

  auto stageK = [&](int kt, int buf) {
    char* base = smem + buf * 16384;
#pragma unroll
    for (int i = 0; i < 4; i++) {
      int lin = i * 256 + tid;
      int key = lin >> 4;
      int c = ((lin & 15) * 8) ^ ((key & 7) * 8);
      gload_lds16(qb + (size_t)(kt * 64 + key) * C_DIM + c, base + lin * 16);
    }
  };
  auto stageV = [&](int kt, int buf) {
    char* base = smem + 32768 + buf * 16384;
#pragma unroll
    for (int i = 0; i < 4; i++) {
      int lin = i * 256 + tid;
      int c = lin >> 3;
      int key = ((lin & 7) * 8) ^ ((c & 7) * 8);
      gload_lds16(vb + (size_t)c * N_TOK + kt * 64 + key, base + lin * 16);
    }
  };

  const float scale = 0.08838834764831845f;  // 1/sqrt(128)
  float m[4], l[4], invl[4];
#pragma unroll
  for (int r = 0; r < 4; r++) { m[r] = -1e30f; l[r] = 0.f; }

  // ---- Sweep 1: partial row max + sumexp over this wave's key half ----
  stageK(0, 0);
  __syncthreads();
  for (int kt = 0; kt < 64; kt++) {
    if (kt + 1 < 64) stageK(kt + 1, (kt + 1) & 1);
    const char* kb = smem + (kt & 1) * 16384;
    float s_all[2][4];
#pragma unroll
    for (int nt16 = 0; nt16 < 2; nt16++) {
      const int nt = kh * 2 + nt16;
      f32x4 acc = {0.f, 0.f, 0.f, 0.f};
#pragma unroll
      for (int ks = 0; ks < 4; ks++) {
        bf16x8 bk = *(const bf16x8*)(kb + nt * 4096 + krow + koff[ks]);
        acc = __builtin_amdgcn_mfma_f32_16x16x32_bf16(qf[ks], bk, acc, 0, 0, 0);
      }
#pragma unroll
      for (int r = 0; r < 4; r++) s_all[nt16][r] = acc[r] * scale;
    }
#pragma unroll
    for (int r = 0; r < 4; r++) {
      float mx = fmaxf(s_all[0][r], s_all[1][r]);
      mx = fmaxf(mx, __shfl_xor(mx, 1));
      mx = fmaxf(mx, __shfl_xor(mx, 2));
      mx = fmaxf(mx, __shfl_xor(mx, 4));
      mx = fmaxf(mx, __shfl_xor(mx, 8));
      float mn = fmaxf(m[r], mx);
      float sum = exp2f((s_all[0][r] - mn) * LOG2E) + exp2f((s_all[1][r] - mn) * LOG2E);
      sum += __shfl_xor(sum, 1);
      sum += __shfl_xor(sum, 2);
      sum += __shfl_xor(sum, 4);
      sum += __shfl_xor(sum, 8);
      l[r] = l[r] * exp2f((m[r] - mn) * LOG2E) + sum;
      m[r] = mn;
    }
    __syncthreads();
  }

  // ---- merge stats across key-halves (intra-block, LDS) ----
  float* statsL = (float*)(smem + 70656);  // [kh][rg][16][2]
  if (l15 == 0) {
#pragma unroll
    for (int r = 0; r < 4; r++) {
      float* p = statsL + (((kh * 2 + rg) * 16) + lg * 4 + r) * 2;
      p[0] = m[r];
      p[1] = l[r];
    }
  }
  __syncthreads();
#pragma unroll
  for (int r = 0; r < 4; r++) {
    const int row = lg * 4 + r;
    const float* p0 = statsL + ((rg * 16) + row) * 2;
    const float* p1 = statsL + (((2 + rg) * 16) + row) * 2;
    float m0 = p0[0], l0 = p0[1], m1 = p1[0], l1 = p1[1];
    float M = fmaxf(m0, m1);
    float L = l0 * exp2f((m0 - M) * LOG2E) + l1 * exp2f((m1 - M) * LOG2E);
    m[r] = M;
    invl[r] = 1.0f / L;
  }

  // ---- Sweep 2: recompute S, write atn, partial PV ----
  f32x4 yacc[8];
#pragma unroll
  for (int ct = 0; ct < 8; ct++) yacc[ct] = {0.f, 0.f, 0.f, 0.f};

  stageK(0, 0);
  stageV(0, 0);
  __syncthreads();
  unsigned short* pb = (unsigned short*)(smem + 65536 + wave * 1280);  // [16][40]
  float* atnb = atn + ((size_t)b * N_TOK + row0) * N_TOK;

  for (int kt = 0; kt < 64; kt++) {
    if (kt + 1 < 64) { stageK(kt + 1, (kt + 1) & 1); stageV(kt + 1, (kt + 1) & 1); }
    const char* kb = smem + (kt & 1) * 16384;
    const char* vbf = smem + 32768 + (kt & 1) * 16384;
#pragma unroll
    for (int nt16 = 0; nt16 < 2; nt16++) {
      const int nt = kh * 2 + nt16;
      f32x4 acc = {0.f, 0.f, 0.f, 0.f};
#pragma unroll
      for (int ks = 0; ks < 4; ks++) {
        bf16x8 bk = *(const bf16x8*)(kb + nt * 4096 + krow + koff[ks]);
        acc = __builtin_amdgcn_mfma_f32_16x16x32_bf16(qf[ks], bk, acc, 0, 0, 0);
      }
#pragma unroll
      for (int r = 0; r < 4; r++) {
        float p = exp2f((acc[r] * scale - m[r]) * LOG2E) * invl[r];
        atnb[(size_t)(lg * 4 + r) * N_TOK + kt * 64 + kh * 32 + nt16 * 16 + l15] = p;
        pb[(lg * 4 + r) * 40 + nt16 * 16 + l15] = (unsigned short)f2bf(p);
      }
    }
    // PV partial: A = P [16 rows][32 keys of this half], B = V chunk kh
    {
      bf16x8 ap = *(const bf16x8*)(pb + l15 * 40 + lg * 8);
#pragma unroll
      for (int ct = 0; ct < 8; ct++) {
        bf16x8 bv = *(const bf16x8*)(vbf + ct * 2048 + vrow + koff2);
        yacc[ct] = __builtin_amdgcn_mfma_f32_16x16x32_bf16(ap, bv, yacc[ct], 0, 0, 0);
      }
    }
    __syncthreads();
  }

  // ---- merge PV partials across key-halves, fused project_out ----
  float* ymergeF = (float*)(smem + 32768);  // [2 rg][16][136] f32 (reuses vbuf)
  if (kh) {
#pragma unroll
    for (int ct = 0; ct < 8; ct++)
#pragma unroll
      for (int r = 0; r < 4; r++)
        ymergeF[(rg * 16 + lg * 4 + r) * 136 + ct * 16 + l15] = yacc[ct][r];
  }
  __syncthreads();
  if (!kh) {
#pragma unroll
    for (int ct = 0; ct < 8; ct++)
#pragma unroll
      for (int r = 0; r < 4; r++)
        yacc[ct][r] += ymergeF[(rg * 16 + lg * 4 + r) * 136 + ct * 16 + l15];

    unsigned short* yl = (unsigned short*)(smem + rg * 16384);  // [16][136] bf16
    float* ol = (float*)(smem + rg * 16384 + 4608);             // [128][20] f32
#pragma unroll
    for (int ct = 0; ct < 8; ct++)
#pragma unroll
      for (int r = 0; r < 4; r++)
        yl[(lg * 4 + r) * 136 + ct * 16 + l15] = f2bf(yacc[ct][r]);

    bf16x8 af[4];
#pragma unroll
    for (int ks = 0; ks < 4; ks++)
      af[ks] = *(const bf16x8*)(yl + l15 * 136 + ks * 32 + lg * 8);

#pragma unroll
    for (int cot = 0; cot < 8; cot++) {
      f32x4 oacc = {0.f, 0.f, 0.f, 0.f};
#pragma unroll
      for (int ks = 0; ks < 4; ks++) {
        const float* wp = w_out + (cot * 16 + l15) * C_DIM + ks * 32 + lg * 8;
        float4 w0 = *(const float4*)wp;
        float4 w1 = *(const float4*)(wp + 4);
        bf16x8 bw;
#pragma unroll
        for (int e = 0; e < 8; e++) bw[e] = (short)f2bf((e < 4) ? (&w0.x)[e] : (&w1.x)[e - 4]);
        oacc = __builtin_amdgcn_mfma_f32_16x16x32_bf16(af[ks], bw, oacc, 0, 0, 0);
      }
      float bo = b_out[cot * 16 + l15];
#pragma unroll
      for (int r = 0; r < 4; r++) ol[(cot * 16 + l15) * 20 + lg * 4 + r] = oacc[r] + bo;
    }
#pragma unroll
    for (int i = 0; i < 2; i++) {
      int co = i * 64 + lane;
      float* dst = yout + ((size_t)b * C_DIM + co) * N_TOK + row0;
      const float* s = ol + co * 20;
#pragma unroll
      for (int jj = 0; jj < 16; jj += 4) *(float4*)(dst + jj) = *(const float4*)(s + jj);
    }
  }
}

extern "C" void kernel_launch(void* const* d_in, const int* in_sizes, int n_in,
                              void* d_out, int out_size, void* d_ws, size_t ws_size,
                              hipStream_t stream) {
  const float* x = (const float*)d_in[0];
  const float* w_inp = (const float*)d_in[1];
  const float* b_inp = (const float*)d_in[2];
  const float* gamma = (const float*)d_in[3];
  const float* beta = (const float*)d_in[4];
  const float* mean = (const float*)d_in[5];
  const float* var = (const float*)d_in[6];
  const float* w_out = (const float*)d_in[7];
  const float* b_out = (const float*)d_in[8];

  float* out = (float*)d_out;
  float* yout = out;                              // [4][128][4096]
  float* atn = out + (size_t)NB * C_DIM * N_TOK;  // [4][4096][4096]

  unsigned short* q = (unsigned short*)d_ws;            // [4][4096][128] bf16
  unsigned short* vT = q + (size_t)NB * N_TOK * C_DIM;  // [4][128][4096] bf16

  proj_in_kernel<<<256, 256, 0, stream>>>(x, w_inp, b_inp, gamma, beta, mean, var, q, vT);
  attn_kernel<<<512, 256, 0, stream>>>(q, vT, w_out, b_out, yout, atn);
}